// Round 4
// baseline (99.432 us; speedup 1.0000x reference)
//
#include <hip/hip_runtime.h>
#include <cstdint>

#ifndef __has_builtin
#define __has_builtin(x) 0
#endif

// Extract bit `off` of x and sign-extend: returns 0 or -1 (all-ones mask).
__device__ __forceinline__ int sbfe1(unsigned x, int off) {
#if __has_builtin(__builtin_amdgcn_sbfe)
    return __builtin_amdgcn_sbfe((int)x, off, 1);
#else
    return ((int)(x << (31 - off))) >> 31;
#endif
}

// Packed mask word for (t, g), pure bit math (matches the reference's integer
// sign construction exactly). 16 pairs (r,q), layout:
//   bit pi    : sign of gp term (1 = negative)
//   bit 16+pi : wedge condition (m subset of i)
//   bit 32+pi : inner condition (m&i==0 or i subset of m)
// where i = 4t+r, m = 4g+q, j = m^i, pi = r*4+q.
__device__ __forceinline__ unsigned long long make_mask_word_bits(int t, int g) {
    unsigned long long word = 0ull;
#pragma unroll
    for (int r = 0; r < 4; ++r) {
#pragma unroll
        for (int q = 0; q < 4; ++q) {
            const int i = 4 * t + r;
            const int m = 4 * g + q;
            const int j = m ^ i;
            const int pi = r * 4 + q;
            int cnt = 0;
#pragma unroll
            for (int p = 0; p < 8; ++p)
                cnt += ((j >> p) & 1) ? __popc(m & ((1 << p) - 1)) : 0;
            if (cnt & 1)                           word |= (1ull << pi);
            if ((m & ~i) == 0)                     word |= (1ull << (16 + pi));
            if (((m & i) == 0) || ((i & ~m) == 0)) word |= (1ull << (32 + pi));
        }
    }
    return word;
}

__global__ void clifford_prep_kernel(unsigned long long* __restrict__ tbl) {
    const int tid = blockIdx.x * blockDim.x + threadIdx.x;  // [0, 4096)
    tbl[tid] = make_mask_word_bits(tid & 63, tid >> 6);     // idx = g*64 + t
}

// 4 rows per block, 512 threads; 8 waves split the m-range (8 groups each).
// Per term: sign applied to B via xor, wedge/inner by masking the B operand,
// then pure FMAs -> 28 VALU/term (was 32).
__global__ __launch_bounds__(512) void clifford_main_kernel(
        const float* __restrict__ A, const float* __restrict__ B,
        const unsigned long long* __restrict__ tbl,
        float* __restrict__ out) {
    __shared__ float As[4][256];
    __shared__ float Bs[4][256];
    __shared__ unsigned long long masks[4096];  // 32 KB; reused as red[8][4][256]

    const int tid = threadIdx.x;   // 0..511
    const int r0 = blockIdx.x * 4; // rows r0..r0+3

    {
        const int row = tid >> 8;  // 0..1
        const int c = tid & 255;
        As[row][c]     = A[(r0 + row) * 256 + c];
        As[row + 2][c] = A[(r0 + row + 2) * 256 + c];
        Bs[row][c]     = B[(r0 + row) * 256 + c];
        Bs[row + 2][c] = B[(r0 + row + 2) * 256 + c];
    }
    if (tbl) {
#pragma unroll
        for (int k2 = 0; k2 < 8; ++k2)
            masks[k2 * 512 + tid] = tbl[k2 * 512 + tid];
    } else {
        for (int k2 = 0; k2 < 8; ++k2) {
            const int idx = k2 * 512 + tid;
            masks[idx] = make_mask_word_bits(idx & 63, idx >> 6);
        }
    }
    __syncthreads();

    const int w = tid >> 6;  // wave id 0..7: m-range split
    const int t = tid & 63;  // thread owns outputs i = 4t+r

    float acc[4][3][4] = {};  // [row][prod][r]

#pragma unroll 2
    for (int gg = 0; gg < 8; ++gg) {
        const int g = (w << 3) | gg;  // this wave's m-group
        const unsigned long long mw = masks[(g << 6) | t];
        float av[4][4];
        unsigned bvu[4][4];
#pragma unroll
        for (int row = 0; row < 4; ++row) {
            const float4 a4 = ((const float4*)As[row])[g ^ t];  // XOR-permuted
            const float4 b4 = ((const float4*)Bs[row])[g];      // broadcast
            av[row][0] = a4.x; av[row][1] = a4.y; av[row][2] = a4.z; av[row][3] = a4.w;
            bvu[row][0] = __float_as_uint(b4.x); bvu[row][1] = __float_as_uint(b4.y);
            bvu[row][2] = __float_as_uint(b4.z); bvu[row][3] = __float_as_uint(b4.w);
        }
        const unsigned lo = (unsigned)mw;
        const unsigned hi = (unsigned)(mw >> 32);
#pragma unroll
        for (int r = 0; r < 4; ++r) {
#pragma unroll
            for (int u = 0; u < 4; ++u) {
                const int q = u ^ r;          // m = 4g+q pairs with a-elem u
                const int pi = (r << 2) | q;  // static bit position
                const unsigned smask = ((unsigned)sbfe1(lo, pi)) << 31;  // 0 or 0x80000000
                const unsigned wm = (unsigned)sbfe1(lo, 16 + pi);
                const unsigned im = (unsigned)sbfe1(hi, pi);
#pragma unroll
                for (int row = 0; row < 4; ++row) {
                    const float a = av[row][u];
                    const unsigned bs = bvu[row][q] ^ smask;   // signed B
                    acc[row][0][r] = fmaf(a, __uint_as_float(bs),      acc[row][0][r]);
                    acc[row][1][r] = fmaf(a, __uint_as_float(bs & wm), acc[row][1][r]);
                    acc[row][2][r] = fmaf(a, __uint_as_float(bs & im), acc[row][2][r]);
                }
            }
        }
    }

    // Chunked cross-wave reduction reusing the mask LDS (32 KB per pass):
    // red[w][row][r*64 + t] holds acc for component comp = 4t+r.
    float* red = (float*)masks;
#pragma unroll
    for (int p = 0; p < 3; ++p) {
        __syncthreads();
#pragma unroll
        for (int row = 0; row < 4; ++row)
#pragma unroll
            for (int r = 0; r < 4; ++r)
                red[w * 1024 + row * 256 + (r << 6) + t] = acc[row][p][r];
        __syncthreads();
#pragma unroll
        for (int c = 0; c < 2; ++c) {
            const int idx = (c << 9) + tid;  // 0..1023
            const int row = idx >> 8;
            const int comp = idx & 255;
            const int swz = row * 256 + (comp >> 2) + ((comp & 3) << 6);
            float s = 0.f;
#pragma unroll
            for (int ww = 0; ww < 8; ++ww) s += red[ww * 1024 + swz];
            out[p * 262144 + (r0 + row) * 256 + comp] = s;  // [3][1024][256]
        }
    }
}

extern "C" void kernel_launch(void* const* d_in, const int* in_sizes, int n_in,
                              void* d_out, int out_size, void* d_ws, size_t ws_size,
                              hipStream_t stream) {
    const float* A = (const float*)d_in[0];
    const float* B = (const float*)d_in[1];
    float* out = (float*)d_out;

    unsigned long long* tbl = nullptr;
    if (ws_size >= 4096 * sizeof(unsigned long long)) {
        tbl = (unsigned long long*)d_ws;
        clifford_prep_kernel<<<64, 64, 0, stream>>>(tbl);
    }
    clifford_main_kernel<<<256, 512, 0, stream>>>(A, B, tbl, out);
}

// Round 5
// 96.021 us; speedup vs baseline: 1.0355x; 1.0355x over previous
//
#include <hip/hip_runtime.h>
#include <cstdint>

#ifndef __has_builtin
#define __has_builtin(x) 0
#endif

// Extract bit `off` of x and sign-extend: returns 0 or -1 (all-ones mask).
__device__ __forceinline__ int sbfe1(unsigned x, int off) {
#if __has_builtin(__builtin_amdgcn_sbfe)
    return __builtin_amdgcn_sbfe((int)x, off, 1);
#else
    return ((int)(x << (31 - off))) >> 31;
#endif
}

// Packed mask word for (t, g), computed from pure bit math (matches the
// reference's integer sign construction exactly). 16 pairs (r,q), layout:
//   bit pi    : sign of gp term (1 = negative)
//   bit 16+pi : wedge condition (m subset of i)
//   bit 32+pi : inner condition (m&i==0 or i subset of m)
// where i = 4t+r, m = 4g+q, j = m^i, pi = r*4+q.
__device__ __forceinline__ unsigned long long make_mask_word_bits(int t, int g) {
    unsigned long long word = 0ull;
#pragma unroll
    for (int r = 0; r < 4; ++r) {
#pragma unroll
        for (int q = 0; q < 4; ++q) {
            const int i = 4 * t + r;
            const int m = 4 * g + q;
            const int j = m ^ i;
            const int pi = r * 4 + q;
            int cnt = 0;
#pragma unroll
            for (int p = 0; p < 8; ++p)
                cnt += ((j >> p) & 1) ? __popc(m & ((1 << p) - 1)) : 0;
            if (cnt & 1)                           word |= (1ull << pi);
            if ((m & ~i) == 0)                     word |= (1ull << (16 + pi));
            if (((m & i) == 0) || ((i & ~m) == 0)) word |= (1ull << (32 + pi));
        }
    }
    return word;
}

__global__ void clifford_prep_kernel(unsigned long long* __restrict__ tbl) {
    const int tid = blockIdx.x * blockDim.x + threadIdx.x;  // [0, 4096)
    tbl[tid] = make_mask_word_bits(tid & 63, tid >> 6);     // idx = g*64 + t
}

// 4 rows per block, 512 threads; 8 waves split the m-range (8 groups each).
// Mask extraction amortized over 4 rows. Product form mul+xor+and+add (all
// VOP2, 4B encodings) — measured faster than the VOP3 fma form (R4 A/B).
__global__ __launch_bounds__(512) void clifford_main_kernel(
        const float* __restrict__ A, const float* __restrict__ B,
        const unsigned long long* __restrict__ tbl,
        float* __restrict__ out) {
    __shared__ float As[4][256];
    __shared__ float Bs[4][256];
    __shared__ unsigned long long masks[4096];  // 32 KB; reused as red[8][4][256]

    const int tid = threadIdx.x;   // 0..511
    const int r0 = blockIdx.x * 4; // rows r0..r0+3

    {
        const int row = tid >> 8;  // 0..1
        const int c = tid & 255;
        As[row][c]     = A[(r0 + row) * 256 + c];
        As[row + 2][c] = A[(r0 + row + 2) * 256 + c];
        Bs[row][c]     = B[(r0 + row) * 256 + c];
        Bs[row + 2][c] = B[(r0 + row + 2) * 256 + c];
    }
    if (tbl) {
#pragma unroll
        for (int k2 = 0; k2 < 8; ++k2)
            masks[k2 * 512 + tid] = tbl[k2 * 512 + tid];
    } else {
        for (int k2 = 0; k2 < 8; ++k2) {
            const int idx = k2 * 512 + tid;
            masks[idx] = make_mask_word_bits(idx & 63, idx >> 6);
        }
    }
    __syncthreads();

    const int w = tid >> 6;  // wave id 0..7: m-range split
    const int t = tid & 63;  // thread owns outputs i = 4t+r

    float acc[4][3][4] = {};  // [row][prod][r]

#pragma unroll 2
    for (int gg = 0; gg < 8; ++gg) {
        const int g = (w << 3) | gg;  // this wave's m-group
        const unsigned long long mw = masks[(g << 6) | t];
        float av[4][4], bv[4][4];
#pragma unroll
        for (int row = 0; row < 4; ++row) {
            const float4 a4 = ((const float4*)As[row])[g ^ t];  // XOR-permuted
            const float4 b4 = ((const float4*)Bs[row])[g];      // broadcast
            av[row][0] = a4.x; av[row][1] = a4.y; av[row][2] = a4.z; av[row][3] = a4.w;
            bv[row][0] = b4.x; bv[row][1] = b4.y; bv[row][2] = b4.z; bv[row][3] = b4.w;
        }
        const unsigned lo = (unsigned)mw;
        const unsigned hi = (unsigned)(mw >> 32);
#pragma unroll
        for (int r = 0; r < 4; ++r) {
#pragma unroll
            for (int u = 0; u < 4; ++u) {
                const int q = u ^ r;          // m = 4g+q pairs with a-elem u
                const int pi = (r << 2) | q;  // static bit position
                const unsigned smask = ((unsigned)sbfe1(lo, pi)) & 0x80000000u;
                const unsigned wm = (unsigned)sbfe1(lo, 16 + pi);
                const unsigned im = (unsigned)sbfe1(hi, pi);
#pragma unroll
                for (int row = 0; row < 4; ++row) {
                    const float p = av[row][u] * bv[row][q];
                    const unsigned pu = __float_as_uint(p) ^ smask;
                    acc[row][0][r] += __uint_as_float(pu);
                    acc[row][1][r] += __uint_as_float(pu & wm);
                    acc[row][2][r] += __uint_as_float(pu & im);
                }
            }
        }
    }

    // Chunked cross-wave reduction reusing the mask LDS (32 KB per pass):
    // red[w][row][r*64 + t] holds acc for component comp = 4t+r.
    float* red = (float*)masks;
#pragma unroll
    for (int p = 0; p < 3; ++p) {
        __syncthreads();
#pragma unroll
        for (int row = 0; row < 4; ++row)
#pragma unroll
            for (int r = 0; r < 4; ++r)
                red[w * 1024 + row * 256 + (r << 6) + t] = acc[row][p][r];
        __syncthreads();
#pragma unroll
        for (int c = 0; c < 2; ++c) {
            const int idx = (c << 9) + tid;  // 0..1023
            const int row = idx >> 8;
            const int comp = idx & 255;
            const int swz = row * 256 + (comp >> 2) + ((comp & 3) << 6);
            float s = 0.f;
#pragma unroll
            for (int ww = 0; ww < 8; ++ww) s += red[ww * 1024 + swz];
            out[p * 262144 + (r0 + row) * 256 + comp] = s;  // [3][1024][256]
        }
    }
}

extern "C" void kernel_launch(void* const* d_in, const int* in_sizes, int n_in,
                              void* d_out, int out_size, void* d_ws, size_t ws_size,
                              hipStream_t stream) {
    const float* A = (const float*)d_in[0];
    const float* B = (const float*)d_in[1];
    float* out = (float*)d_out;

    unsigned long long* tbl = nullptr;
    if (ws_size >= 4096 * sizeof(unsigned long long)) {
        tbl = (unsigned long long*)d_ws;
        clifford_prep_kernel<<<64, 64, 0, stream>>>(tbl);
    }
    clifford_main_kernel<<<256, 512, 0, stream>>>(A, B, tbl, out);
}